// Round 9
// baseline (147.986 us; speedup 1.0000x reference)
//
#include <hip/hip_runtime.h>
#include <math.h>

// Sizes (fixed by the problem)
#define B_SZ 8
#define T_LEN 4096
#define D_IN 128
#define D_OUT 128
#define N_ST 256
#define BT (B_SZ * T_LEN)        // 32768
#define CHUNK 64                 // scan chunk length
#define NCHUNK (T_LEN / CHUNK)   // 64 chunks per sequence
#define NBLK (B_SZ * NCHUNK)     // 512 chunk-blocks

typedef __attribute__((ext_vector_type(8))) short short8;
typedef __attribute__((ext_vector_type(4))) float f32x4;
typedef unsigned int uint;
typedef unsigned short ushort;

static __device__ __forceinline__ short f2bf(float f) {
  union { float f; uint u; } v; v.f = f;
  uint r = v.u + 0x7FFFu + ((v.u >> 16) & 1u);  // round-to-nearest-even
  return (short)(r >> 16);
}
static __device__ __forceinline__ float bf2f(uint h) {
  union { uint u; float f; } v; v.u = h << 16;
  return v.f;
}
static __device__ __forceinline__ uint pack2(float a, float b) {
  return (uint)(ushort)f2bf(a) | ((uint)(ushort)f2bf(b) << 16);
}

// ---------------------------------------------------------------------------
// k0_setup: R7 VERBATIM (validated). blk<320: weight pack; else lampow2 row.
// Wf1[kg][col][j] = W1[kg*8+j][col], col=2n+ri: gamma_n*(ri?B_im:B_re)[n][k]
// Wf2[kg][d][j]:  k=kg*8+j; k<512: n=k>>1, (k&1)? -C_im[d][n] : C_re[d][n];
//                 k>=512: D[d][k-512]
// ---------------------------------------------------------------------------
__global__ __launch_bounds__(256) void k0_setup(
    const float* __restrict__ nu_log, const float* __restrict__ theta_log,
    const float* __restrict__ gamma_log,
    const float* __restrict__ B_re, const float* __restrict__ B_im,
    const float* __restrict__ C_re, const float* __restrict__ C_im,
    const float* __restrict__ Dm,
    short* __restrict__ Wf1, short* __restrict__ Wf2,
    float2* __restrict__ lampow2) {
  int blk = blockIdx.x;
  if (blk < 320) {
    int idx = blk * 256 + threadIdx.x;
    if (idx < 16 * 512 * 8) {
      int j = idx & 7, col = (idx >> 3) & 511, kg = idx >> 12;
      int k = kg * 8 + j;
      int n = col >> 1, ri = col & 1;
      float g = expf(gamma_log[n]);
      float v = g * (ri ? B_im[n * D_IN + k] : B_re[n * D_IN + k]);
      Wf1[idx] = f2bf(v);
    }
    if (idx < 80 * 128 * 8) {
      int j = idx & 7, d = (idx >> 3) & 127, kg = idx >> 10;
      int k = kg * 8 + j;
      float v;
      if (k < 512) {
        int n = k >> 1;
        v = (k & 1) ? -C_im[d * N_ST + n] : C_re[d * N_ST + n];
      } else {
        v = Dm[d * D_IN + (k - 512)];
      }
      Wf2[idx] = f2bf(v);
    }
  } else {
    int j = blk - 320;  // 0..64
    int n = threadIdx.x;
    float e_nu = expf(nu_log[n]);
    float phase = expf(theta_log[n]);
    float r = expf(-(float)j * e_nu);
    float a = (float)j * phase;
    float2 v; v.x = r * cosf(a); v.y = r * sinf(a);
    lampow2[j * N_ST + n] = v;
  }
}

// ---------------------------------------------------------------------------
// kA: R2/R7 VERBATIM (validated). Fused GEMM1 (bf16 MFMA) + local chunk scan
// -> global bf16 states + chunk carry E.
// ---------------------------------------------------------------------------
__global__ __launch_bounds__(256, 2) void kA(
    const float* __restrict__ x, const short* __restrict__ Wf1,
    const float2* __restrict__ lampow2,
    uint* __restrict__ states, float2* __restrict__ E) {
  __shared__ short bu[64 * 520];   // row-major, +8 pad per row

  int bc = blockIdx.x;
  size_t row0 = (size_t)bc * CHUNK;
  int tid = threadIdx.x;
  int lane = tid & 63, w = tid >> 6;
  int m = lane & 15, q = lane >> 4;

  f32x4 acc[32];
#pragma unroll
  for (int ct = 0; ct < 32; ++ct) acc[ct] = (f32x4){0.f, 0.f, 0.f, 0.f};

  const float* xrow = x + (row0 + 16 * w + m) * D_IN;

  for (int ks = 0; ks < 4; ++ks) {
    float4 xa = *(const float4*)(xrow + 32 * ks + 8 * q);
    float4 xb = *(const float4*)(xrow + 32 * ks + 8 * q + 4);
    short8 af;
    af[0] = f2bf(xa.x); af[1] = f2bf(xa.y); af[2] = f2bf(xa.z); af[3] = f2bf(xa.w);
    af[4] = f2bf(xb.x); af[5] = f2bf(xb.y); af[6] = f2bf(xb.z); af[7] = f2bf(xb.w);
    const short* wbase = Wf1 + ((size_t)(4 * ks + q) * 512 + m) * 8;
#pragma unroll
    for (int ct = 0; ct < 32; ++ct) {
      short8 bf = *(const short8*)(wbase + 16 * ct * 8);
      acc[ct] = __builtin_amdgcn_mfma_f32_16x16x32_bf16(af, bf, acc[ct], 0, 0, 0);
    }
  }

  // write Bu tile to LDS (bf16). C-layout: row=4q+r, col=m within 16x16 tile.
#pragma unroll
  for (int ct = 0; ct < 32; ++ct) {
#pragma unroll
    for (int r = 0; r < 4; ++r) {
      bu[(16 * w + 4 * q + r) * 520 + 16 * ct + m] = f2bf(acc[ct][r]);
    }
  }
  __syncthreads();

  // scan: thread n owns state n
  int n = tid;
  float2 lam = lampow2[N_ST + n];  // lam^1
  float sre = 0.f, sim = 0.f;
  uint* sg = states + row0 * N_ST + n;
  for (int j = 0; j < CHUNK; ++j) {
    uint p = ((const uint*)(bu + j * 520))[n];
    float br = bf2f(p & 0xffffu), bi = bf2f(p >> 16);
    float nr = fmaf(lam.x, sre, fmaf(-lam.y, sim, br));
    float ni = fmaf(lam.x, sim, fmaf(lam.y, sre, bi));
    sre = nr; sim = ni;
    sg[(size_t)j * N_ST] = pack2(sre, sim);
  }
  float2 e; e.x = sre; e.y = sim;
  E[bc * N_ST + n] = e;
}

// ---------------------------------------------------------------------------
// kC: R7 kC with kB FOLDED IN. Prologue: per-block incoming carry P computed
// with kB's bit-identical recurrence from E (1 MB, L2-hot). Then R7 kC
// verbatim: states fix-up -> swizzled As, x -> As, GEMM2 (K=640) -> y.
// ---------------------------------------------------------------------------
__global__ __launch_bounds__(256, 2) void kC(
    const float* __restrict__ x, const uint* __restrict__ states,
    const float2* __restrict__ E, const float2* __restrict__ lampow2,
    const short* __restrict__ Wf2, float* __restrict__ y) {
  __shared__ short As[64 * 640];   // exactly 80 KB

  int bc = blockIdx.x;
  size_t row0 = (size_t)bc * CHUNK;
  int tid = threadIdx.x;

  // ---- in-kernel carry (kB's recurrence, prefix at step c; bit-identical) --
  int n = tid;
  float pre = 0.f, pim = 0.f;
  {
    float2 lamL = lampow2[CHUNK * N_ST + n];  // lam^64
    int c = bc & (NCHUNK - 1), b = bc >> 6;
    for (int j = 0; j < c; ++j) {
      float2 e = E[(size_t)((b << 6) + j) * N_ST + n];
      float nre = fmaf(lamL.x, pre, fmaf(-lamL.y, pim, e.x));
      float nim = fmaf(lamL.x, pim, fmaf(lamL.y, pre, e.y));
      pre = nre; pim = nim;
    }
  }

  // phase 1a: states fix-up -> LDS (R7 verbatim, P replaced by {pre,pim})
  {
    int g = n >> 2;
    int koff = (2 * n) & 7;
    for (int row = 0; row < CHUNK; ++row) {
      uint sp = states[(row0 + row) * N_ST + n];
      float2 lp = lampow2[(row + 1) * N_ST + n];
      float sr = bf2f(sp & 0xffffu) + lp.x * pre - lp.y * pim;
      float si = bf2f(sp >> 16) + lp.x * pim + lp.y * pre;
      int gp = (g & ~7) | ((g + row) & 7);
      *(uint*)(As + row * 640 + gp * 8 + koff) = pack2(sr, si);
    }
  }
  // phase 1b: x -> LDS bf16 (cols 512..639) (R7 verbatim)
  {
    int kxp = tid & 63, r0 = tid >> 6;
    int k = 512 + 2 * kxp;
    int g = k >> 3, koff = k & 7;
    for (int rr = 0; rr < 16; ++rr) {
      int row = r0 * 16 + rr;
      float2 xv = *(const float2*)(x + (row0 + row) * D_IN + 2 * kxp);
      int gp = (g & ~7) | ((g + row) & 7);
      *(uint*)(As + row * 640 + gp * 8 + koff) = pack2(xv.x, xv.y);
    }
  }
  __syncthreads();

  // phase 2: MFMA (R7 verbatim). wave w -> rows 16w..16w+15; 8 col-tiles.
  int lane = tid & 63, w = tid >> 6;
  int m = lane & 15, q = lane >> 4;
  int arow = 16 * w + m;

  f32x4 acc[8];
#pragma unroll
  for (int ct = 0; ct < 8; ++ct) acc[ct] = (f32x4){0.f, 0.f, 0.f, 0.f};

  for (int ks = 0; ks < 20; ++ks) {
    int g = 4 * ks + q;
    int gp = (g & ~7) | ((g + arow) & 7);
    short8 af = *(const short8*)(As + arow * 640 + gp * 8);
    const short* wbase = Wf2 + ((size_t)g * 128 + m) * 8;
#pragma unroll
    for (int ct = 0; ct < 8; ++ct) {
      short8 bf = *(const short8*)(wbase + 16 * ct * 8);
      acc[ct] = __builtin_amdgcn_mfma_f32_16x16x32_bf16(af, bf, acc[ct], 0, 0, 0);
    }
  }

#pragma unroll
  for (int ct = 0; ct < 8; ++ct) {
#pragma unroll
    for (int r = 0; r < 4; ++r) {
      y[(row0 + 16 * w + 4 * q + r) * D_OUT + 16 * ct + m] = acc[ct][r];
    }
  }
}

// ---------------------------------------------------------------------------
extern "C" void kernel_launch(void* const* d_in, const int* in_sizes, int n_in,
                              void* d_out, int out_size, void* d_ws, size_t ws_size,
                              hipStream_t stream) {
  const float* x         = (const float*)d_in[0];
  const float* nu_log    = (const float*)d_in[1];
  const float* theta_log = (const float*)d_in[2];
  const float* gamma_log = (const float*)d_in[3];
  const float* B_re      = (const float*)d_in[4];
  const float* B_im      = (const float*)d_in[5];
  const float* C_re      = (const float*)d_in[6];
  const float* C_im      = (const float*)d_in[7];
  const float* Dm        = (const float*)d_in[8];
  float* y = (float*)d_out;

  char* wp = (char*)d_ws;
  float2* lampow2 = (float2*)wp; wp += (size_t)(CHUNK + 1) * N_ST * sizeof(float2);
  short*  Wf1     = (short*)wp;  wp += (size_t)16 * 512 * 8 * sizeof(short);
  short*  Wf2     = (short*)wp;  wp += (size_t)80 * 128 * 8 * sizeof(short);
  float2* E       = (float2*)wp; wp += (size_t)NBLK * N_ST * sizeof(float2);
  uint*   states  = (uint*)wp;   wp += (size_t)BT * N_ST * sizeof(uint);

  hipLaunchKernelGGL(k0_setup, dim3(385), dim3(256), 0, stream,
                     nu_log, theta_log, gamma_log, B_re, B_im, C_re, C_im, Dm,
                     Wf1, Wf2, lampow2);
  hipLaunchKernelGGL(kA, dim3(NBLK), dim3(256), 0, stream,
                     x, Wf1, lampow2, states, E);
  hipLaunchKernelGGL(kC, dim3(NBLK), dim3(256), 0, stream,
                     x, states, E, lampow2, Wf2, y);
}